// Round 6
// baseline (14.418 us; speedup 1.0000x reference)
//
#include <hip/hip_runtime.h>
#include <math.h>

#define BB 8
#define NN 2048
#define NVARS 64
#define HH 32

// One block per (batch, var) bucket, single launch.
// Pre-barrier:  wave 0 folds weights (k split across lane halves);
//               waves 1-3 PREFETCH the row (vec4) into registers.
// Barrier 1 (drains vmcnt) -> appends are LDS-only.
// Phase B: lane-parallel MLP (thread=(obs,j), shfl-reduce) -> sr, e=sr*exp(t/tau),
//          ei=rcp(exp(t/tau))=exp(-t/tau).
// Phase C: pair sum = ei_n * sum_{t_m<t_n} e_m; 1-tanh(x)=2q/(1+q), q=exp(-2x).
__global__ __launch_bounds__(256) void fused_kernel(
    const float* __restrict__ value, const float* __restrict__ time_norm,
    const float* __restrict__ mask,  const int*   __restrict__ var_id,
    const float* __restrict__ var_emb,
    const float* __restrict__ W1, const float* __restrict__ b1,
    const float* __restrict__ W2, const float* __restrict__ b2,
    const float* __restrict__ gate_w, const float* __restrict__ gate_b,
    const float* __restrict__ log_tau_r, const float* __restrict__ log_alpha,
    float* __restrict__ out)
{
    __shared__ float s_t[NN], s_f0[NN], s_mk[NN], s_sr[NN], s_e[NN], s_ei[NN];
    __shared__ int   s_idx[NN];
    __shared__ float s_base1[HH], s_w1v[HH], s_w1t[HH], s_w1m[HH], s_w2g[HH];
    __shared__ float s_c;
    __shared__ int   s_cnt;

    const int b    = blockIdx.x >> 6;
    const int var  = blockIdx.x & 63;
    const int base = b * NN;
    const int tid  = threadIdx.x;

    const float inv_tau = 1.0f / fmaxf(__expf(log_tau_r[var]), 1e-6f);
    const float alpha   = __expf(log_alpha[var]);

    // scan-prefetch registers (persist across the barrier)
    int4   va, vb, vc = make_int4(-1, -1, -1, -1);
    float4 ta, tb, tc, la, lb, lc, ma, mb, mc;
    int i0 = 0, i1 = 0, i2 = 0;

    if (tid < 64) {
        if (tid == 0) s_cnt = 0;
        // ---- weight fold, k split across the two 32-lane halves of wave 0 ----
        const int jj = tid & 31, h = tid >> 5;
        float accB = 0.0f;
        #pragma unroll
        for (int k = 0; k < 16; ++k) {
            const int kk = k + 16 * h;
            accB += var_emb[var * HH + kk] * W1[(3 + kk) * HH + jj];
        }
        accB += __shfl_xor(accB, 32);      // combine halves (64-lane wave)
        if (h == 0) {
            s_base1[jj] = accB + b1[jj];
            s_w1v[jj] = W1[0 * HH + jj];
            s_w1t[jj] = W1[1 * HH + jj];
            s_w1m[jj] = W1[2 * HH + jj];
        } else {
            const float4* W2r = reinterpret_cast<const float4*>(W2 + jj * HH);
            float a = 0.0f;
            #pragma unroll
            for (int q = 0; q < 8; ++q) {
                const float4 w = W2r[q];
                a += w.x * gate_w[4 * q + 0] + w.y * gate_w[4 * q + 1]
                   + w.z * gate_w[4 * q + 2] + w.w * gate_w[4 * q + 3];
            }
            s_w2g[jj] = a;
        }
        if (tid == 0) {
            float acc = gate_b[0];
            #pragma unroll
            for (int q = 0; q < HH; ++q) acc += b2[q] * gate_w[q];
            s_c = acc;
        }
    } else {
        // ---- prefetch row slices into registers (loads drain at barrier 1) ----
        const int ts = tid - 64;            // 0..191
        i0 = ts * 4; i1 = i0 + 768; i2 = i0 + 1536;
        va = *reinterpret_cast<const int4*>(var_id + base + i0);
        ta = *reinterpret_cast<const float4*>(time_norm + base + i0);
        la = *reinterpret_cast<const float4*>(value + base + i0);
        ma = *reinterpret_cast<const float4*>(mask + base + i0);
        vb = *reinterpret_cast<const int4*>(var_id + base + i1);
        tb = *reinterpret_cast<const float4*>(time_norm + base + i1);
        lb = *reinterpret_cast<const float4*>(value + base + i1);
        mb = *reinterpret_cast<const float4*>(mask + base + i1);
        if (i2 < NN) {
            vc = *reinterpret_cast<const int4*>(var_id + base + i2);
            tc = *reinterpret_cast<const float4*>(time_norm + base + i2);
            lc = *reinterpret_cast<const float4*>(value + base + i2);
            mc = *reinterpret_cast<const float4*>(mask + base + i2);
        }
    }
    __syncthreads();

    if (tid >= 64) {
        // LDS-only appends; order irrelevant (strict t_m<t_n pair condition)
        #define APPEND(V, T, L, M, I) \
            if ((V) == var) { int p = atomicAdd(&s_cnt, 1); s_t[p] = (T); \
                s_f0[p] = (L) * (M); s_mk[p] = (M); s_idx[p] = (I); }
        APPEND(va.x, ta.x, la.x, ma.x, i0 + 0) APPEND(va.y, ta.y, la.y, ma.y, i0 + 1)
        APPEND(va.z, ta.z, la.z, ma.z, i0 + 2) APPEND(va.w, ta.w, la.w, ma.w, i0 + 3)
        APPEND(vb.x, tb.x, lb.x, mb.x, i1 + 0) APPEND(vb.y, tb.y, lb.y, mb.y, i1 + 1)
        APPEND(vb.z, tb.z, lb.z, mb.z, i1 + 2) APPEND(vb.w, tb.w, lb.w, mb.w, i1 + 3)
        APPEND(vc.x, tc.x, lc.x, mc.x, i2 + 0) APPEND(vc.y, tc.y, lc.y, mc.y, i2 + 1)
        APPEND(vc.z, tc.z, lc.z, mc.z, i2 + 2) APPEND(vc.w, tc.w, lc.w, mc.w, i2 + 3)
        #undef APPEND
    }
    __syncthreads();
    const int S = s_cnt;

    const int j   = tid & 31;   // hidden unit / m-lane
    const int sub = tid >> 5;   // 0..7 obs subgroup
    const float b1j = s_base1[j], w1vj = s_w1v[j], w1tj = s_w1t[j],
                w1mj = s_w1m[j], w2gj = s_w2g[j], cc = s_c;

    // Phase B: MLP, 8 obs per pass, one GELU term per thread
    for (int n = sub; n < S; n += 8) {
        const float mk = s_mk[n];
        const float f0 = s_f0[n];
        const float f1 = s_t[n];
        const float pre = b1j + f0 * w1vj + f1 * w1tj + mk * w1mj;
        const float g = 0.5f * pre * (1.0f + erff(pre * 0.70710678118654752f));
        float term = g * w2gj;
        #pragma unroll
        for (int off = 16; off > 0; off >>= 1) term += __shfl_xor(term, off, 32);
        if (j == 0) {
            const float sr = mk * __builtin_amdgcn_rcpf(1.0f + __expf(-(term + cc)));
            const float ep = __expf(f1 * inv_tau);
            s_sr[n] = sr;
            s_e[n]  = sr * ep;                        // factored decay numerator
            s_ei[n] = __builtin_amdgcn_rcpf(ep);      // exp(-t_n/tau)
        }
    }
    __syncthreads();

    // Phase C: pure FMA inner loop; epilogue has 1 exp + 1 rcp
    for (int n = sub; n < S; n += 8) {
        const float t_n = s_t[n];
        float acc = 0.0f;
        for (int m = j; m < S; m += 32)
            acc += (s_t[m] < t_n) ? s_e[m] : 0.0f;
        #pragma unroll
        for (int off = 16; off > 0; off >>= 1) acc += __shfl_xor(acc, off, 32);
        if (j == 0) {
            const float x = alpha * (acc * s_ei[n]);              // x >= 0
            const float q = __expf(-2.0f * x);
            // 1 - tanh(x) = 2q/(1+q)
            out[base + s_idx[n]] = s_sr[n] * (2.0f * q) * __builtin_amdgcn_rcpf(1.0f + q);
        }
    }
}

extern "C" void kernel_launch(void* const* d_in, const int* in_sizes, int n_in,
                              void* d_out, int out_size, void* d_ws, size_t ws_size,
                              hipStream_t stream) {
    const float* value     = (const float*)d_in[0];
    const float* time_norm = (const float*)d_in[1];
    const float* mask      = (const float*)d_in[2];
    const int*   var_id    = (const int*)  d_in[3];
    const float* var_emb   = (const float*)d_in[4];
    const float* W1        = (const float*)d_in[5];
    const float* b1        = (const float*)d_in[6];
    const float* W2        = (const float*)d_in[7];
    const float* b2        = (const float*)d_in[8];
    const float* gate_w    = (const float*)d_in[9];
    const float* gate_b    = (const float*)d_in[10];
    const float* log_tau_r = (const float*)d_in[11];
    const float* log_alpha = (const float*)d_in[12];

    float* out = (float*)d_out;

    hipLaunchKernelGGL(fused_kernel, dim3(BB * NVARS), dim3(256), 0, stream,
                       value, time_norm, mask, var_id, var_emb,
                       W1, b1, W2, b2, gate_w, gate_b, log_tau_r, log_alpha, out);
}